// Round 10
// baseline (135.664 us; speedup 1.0000x reference)
//
#include <hip/hip_runtime.h>
#include <math.h>

#define NB 8
#define NQ 100
#define NQH 50
#define NCP1 3
#define NC 2
#define HIN 128
#define WIN 128
#define HOUT 512
#define WOUT 512
#define QSTR (HIN * WIN)

#if __has_builtin(__builtin_amdgcn_exp2f)
#define EXP2F(x) __builtin_amdgcn_exp2f(x)
#else
#define EXP2F(x) exp2f(x)
#endif
#if __has_builtin(__builtin_amdgcn_rcpf)
#define RCPF(x) __builtin_amdgcn_rcpf(x)
#else
#define RCPF(x) (1.0f / (x))
#endif

__device__ __forceinline__ float bperm(int byteaddr, float v) {
  return __int_as_float(__builtin_amdgcn_ds_bpermute(byteaddr, __float_as_int(v)));
}

// R10 = R9 (q-split, 8 waves/SIMD, bperm halo, depth-4 pipeline) + scalar rcp
// product tree: 1 v_rcp serves 8 sigmoids.  R9's counters showed busy time
// ~= trans-pipe time (16 trans/wave-q x 16 cyc = 43us ~= 0.69*64.7) -> we are
// trans-pipe-bound.  Tree cuts trans 16->9 per wave-q (-45% pipe time) for
// +21 VALU muls.  R5's neutral tree result was at 4 waves/SIMD where latency
// stall absorbed the savings; at 8 waves/SIMD it should show.  Numerics
// validated in R4/R5 (absmax 0.125, same as per-pixel rcp).
__global__ __launch_bounds__(512, 4)
void m2f_fused(const float* __restrict__ cls,
               const float* __restrict__ masks,
               float* __restrict__ out) {
  const int k   = blockIdx.x;   // 0..127
  const int b   = blockIdx.y;   // 0..7
  const int tid = threadIdx.x;  // 0..511

  __shared__ float2 pq[NQ];           // (p_class0, p_class1) per q
  __shared__ float  part[16][256];    // qh=1 partials: [j][r*64+lane]

  // ---- inline class softmax (keep first NC of NCP1) ----
  if (tid < NQ) {
    const float* cl = cls + (b * NQ + tid) * NCP1;
    float a0 = cl[0], a1 = cl[1], a2 = cl[2];
    float mx = fmaxf(a0, fmaxf(a1, a2));
    const float L2E = 1.4426950408889634f;
    float e0 = EXP2F((a0 - mx) * L2E);
    float e1 = EXP2F((a1 - mx) * L2E);
    float e2 = EXP2F((a2 - mx) * L2E);
    float inv = RCPF(e0 + e1 + e2);
    pq[tid] = make_float2(e0 * inv, e1 * inv);
  }
  __syncthreads();

  const int wave = tid >> 6;    // 0..7
  const int r    = wave & 3;    // output row phase (y = 4k+r)
  const int qh   = wave >> 2;   // q half: 0 -> q 0..49, 1 -> q 50..99
  const int lane = tid & 63;    // col group: x = 8*lane .. 8*lane+7
  const int q0   = qh * NQH;

  // clamped input rows + vertical weights (pre-scaled by -log2e so
  // sigmoid(x) = rcp(1 + exp2(v)), v = -log2e * x)
  const int rlo = (r < 2) ? (k > 0 ? k - 1 : 0) : k;
  const int rhi = (r < 2) ? k : (k < HIN - 1 ? k + 1 : HIN - 1);
  const float NL2E = -1.4426950408889634f;
  const float wlo = ((r == 0) ? 0.375f : (r == 1) ? 0.125f
                   : (r == 2) ? 0.875f : 0.625f) * NL2E;
  const float whi = ((r == 0) ? 0.625f : (r == 1) ? 0.875f
                   : (r == 2) ? 0.125f : 0.375f) * NL2E;

  const int oA = rlo * WIN + 2 * lane;
  const int oB = rhi * WIN + 2 * lane;
  const float* __restrict__ base = masks + (size_t)b * NQ * QSTR;  // uniform

  const int addrL = (lane - 1) << 2;
  const int addrR = (lane + 1) << 2;
  const bool edgeL = (lane == 0);
  const bool edgeR = (lane == 63);

  float c0[8], c1[8];
#pragma unroll
  for (int j = 0; j < 8; ++j) { c0[j] = 0.f; c1[j] = 0.f; }

  // depth-4 pipeline: 2 x float2 per stage
  float2 A0, B0, A1, B1, A2, B2, A3, B3;

#define LOADSET(S, qq)                                                    \
  do {                                                                    \
    const float* mq = base + (size_t)(qq) * QSTR; /* uniform SGPR adv */  \
    A##S = *(const float2*)(mq + oA);                                     \
    B##S = *(const float2*)(mq + oB);                                     \
  } while (0)

#define COMPUTE(S, qq)                                                    \
  do {                                                                    \
    const float2 pd = pq[qq];                                             \
    float t0 = fmaf(wlo, A##S.x, whi * B##S.x);   /* col 2c   */          \
    float t1 = fmaf(wlo, A##S.y, whi * B##S.y);   /* col 2c+1 */          \
    float tLr = bperm(addrL, t1);                                         \
    float tRr = bperm(addrR, t0);                                         \
    float tL = edgeL ? t0 : tLr;                                          \
    float tR = edgeR ? t1 : tRr;                                          \
    float dm = tL - t0, dd = t1 - t0, dp = tR - t1;                       \
    float v0 = fmaf(0.375f, dm, t0);                                      \
    float v1 = fmaf(0.125f, dm, t0);                                      \
    float v2 = fmaf(0.125f, dd, t0);                                      \
    float v3 = fmaf(0.375f, dd, t0);                                      \
    float v4 = fmaf(0.625f, dd, t0);                                      \
    float v5 = fmaf(0.875f, dd, t0);                                      \
    float v6 = fmaf(0.125f, dp, t1);                                      \
    float v7 = fmaf(0.375f, dp, t1);                                      \
    /* denominators d = 1 + exp2(v) */                                    \
    float d0 = EXP2F(v0) + 1.0f;                                          \
    float d1 = EXP2F(v1) + 1.0f;                                          \
    float d2 = EXP2F(v2) + 1.0f;                                          \
    float d3 = EXP2F(v3) + 1.0f;                                          \
    float d4 = EXP2F(v4) + 1.0f;                                          \
    float d5 = EXP2F(v5) + 1.0f;                                          \
    float d6 = EXP2F(v6) + 1.0f;                                          \
    float d7 = EXP2F(v7) + 1.0f;                                          \
    /* one v_rcp for all 8 sigmoids via product tree (d in (1,2^12)) */   \
    float m0 = d0 * d1, m1 = d2 * d3, m2 = d4 * d5, m3 = d6 * d7;         \
    float n0 = m0 * m1, n1 = m2 * m3;                                     \
    float R  = RCPF(n0 * n1);                                             \
    float rn0 = R * n1, rn1 = R * n0;                                     \
    float rm0 = rn0 * m1, rm1 = rn0 * m0;                                 \
    float rm2 = rn1 * m3, rm3 = rn1 * m2;                                 \
    float s0 = rm0 * d1, s1 = rm0 * d0;                                   \
    float s2 = rm1 * d3, s3 = rm1 * d2;                                   \
    float s4 = rm2 * d5, s5 = rm2 * d4;                                   \
    float s6 = rm3 * d7, s7 = rm3 * d6;                                   \
    c0[0] = fmaf(pd.x, s0, c0[0]);  c1[0] = fmaf(pd.y, s0, c1[0]);        \
    c0[1] = fmaf(pd.x, s1, c0[1]);  c1[1] = fmaf(pd.y, s1, c1[1]);        \
    c0[2] = fmaf(pd.x, s2, c0[2]);  c1[2] = fmaf(pd.y, s2, c1[2]);        \
    c0[3] = fmaf(pd.x, s3, c0[3]);  c1[3] = fmaf(pd.y, s3, c1[3]);        \
    c0[4] = fmaf(pd.x, s4, c0[4]);  c1[4] = fmaf(pd.y, s4, c1[4]);        \
    c0[5] = fmaf(pd.x, s5, c0[5]);  c1[5] = fmaf(pd.y, s5, c1[5]);        \
    c0[6] = fmaf(pd.x, s6, c0[6]);  c1[6] = fmaf(pd.y, s6, c1[6]);        \
    c0[7] = fmaf(pd.x, s7, c0[7]);  c1[7] = fmaf(pd.y, s7, c1[7]);        \
  } while (0)

  LOADSET(0, q0); LOADSET(1, q0 + 1); LOADSET(2, q0 + 2); LOADSET(3, q0 + 3);

  for (int q = 0; q < NQH - 2; q += 4) {
    COMPUTE(0, q0 + q);     if (q + 4 < NQH) LOADSET(0, q0 + q + 4);
    COMPUTE(1, q0 + q + 1); if (q + 5 < NQH) LOADSET(1, q0 + q + 5);
    COMPUTE(2, q0 + q + 2); if (q + 6 < NQH) LOADSET(2, q0 + q + 6);
    COMPUTE(3, q0 + q + 3); if (q + 7 < NQH) LOADSET(3, q0 + q + 7);
  }
  // tail: NQH = 50 = 4*12 + 2 -> stages 0,1 hold q0+48, q0+49
  COMPUTE(0, q0 + NQH - 2);
  COMPUTE(1, q0 + NQH - 1);

  // ---- combine q-halves through LDS (conflict-free: stride-1 per j) ----
  const int col = r * 64 + lane;
  if (qh == 1) {
#pragma unroll
    for (int j = 0; j < 8; ++j) { part[j][col] = c0[j]; part[j + 8][col] = c1[j]; }
  }
  __syncthreads();
  if (qh == 0) {
#pragma unroll
    for (int j = 0; j < 8; ++j) { c0[j] += part[j][col]; c1[j] += part[j + 8][col]; }

    const int y  = 4 * k + r;
    const int x0 = 8 * lane;
    float* o0 = out + (((size_t)b * NC + 0) * HOUT + y) * WOUT + x0;
    float* o1 = out + (((size_t)b * NC + 1) * HOUT + y) * WOUT + x0;
    *(float4*)o0       = make_float4(c0[0], c0[1], c0[2], c0[3]);
    *(float4*)(o0 + 4) = make_float4(c0[4], c0[5], c0[6], c0[7]);
    *(float4*)o1       = make_float4(c1[0], c1[1], c1[2], c1[3]);
    *(float4*)(o1 + 4) = make_float4(c1[4], c1[5], c1[6], c1[7]);
  }
}

extern "C" void kernel_launch(void* const* d_in, const int* in_sizes, int n_in,
                              void* d_out, int out_size, void* d_ws, size_t ws_size,
                              hipStream_t stream) {
  const float* cls   = (const float*)d_in[0];   // [8,100,3] fp32
  const float* masks = (const float*)d_in[1];   // [8,100,128,128] fp32
  float* out = (float*)d_out;                   // [8,2,512,512] fp32
  dim3 grid(HIN, NB);   // 128 k-groups x 8 batches, 8 waves/block
  m2f_fused<<<grid, 512, 0, stream>>>(cls, masks, out);
}

// Round 12
// 129.869 us; speedup vs baseline: 1.0446x; 1.0446x over previous
//
#include <hip/hip_runtime.h>
#include <math.h>

#define NB 8
#define NQ 100
#define NQH 50
#define NCP1 3
#define NC 2
#define HIN 128
#define WIN 128
#define HOUT 512
#define WOUT 512
#define QSTR (HIN * WIN)
#define QBYTES (QSTR * 4)

#if __has_builtin(__builtin_amdgcn_exp2f)
#define EXP2F(x) __builtin_amdgcn_exp2f(x)
#else
#define EXP2F(x) exp2f(x)
#endif
#if __has_builtin(__builtin_amdgcn_rcpf)
#define RCPF(x) __builtin_amdgcn_rcpf(x)
#else
#define RCPF(x) (1.0f / (x))
#endif

__device__ __forceinline__ float bperm(int byteaddr, float v) {
  return __int_as_float(__builtin_amdgcn_ds_bpermute(byteaddr, __float_as_int(v)));
}

// R12 = R11's saddr-load experiment, compile-fixed.  R11 failed because the
// saddr operand included q0 (thread-dependent via wave id) -> not SGPR-able.
// Fix: saddr = masks + b*NQ*QSTR (block-uniform, true SGPR pair); the wave's
// q-half lives in the 32-bit VGPR voffset (q0*65536B folded in at setup;
// per-q displacement qrel*65536 is scalar-mul + 1 v_add per operand).
// Outputs early-clobbered (=&v).  Depth-5 pipeline, manual s_waitcnt
// vmcnt(8) tied to stage regs (compiler can't track asm loads).  Otherwise
// identical to R9 (64.7us best: q-split 8 waves/SIMD, bperm halo, LDS
// combine, per-pixel rcp).
__global__ __launch_bounds__(512, 4)
void m2f_fused(const float* __restrict__ cls,
               const float* __restrict__ masks,
               float* __restrict__ out) {
  const int k   = blockIdx.x;   // 0..127
  const int b   = blockIdx.y;   // 0..7
  const int tid = threadIdx.x;  // 0..511

  __shared__ float2 pq[NQ];           // (p_class0, p_class1) per q
  __shared__ float  part[16][256];    // qh=1 partials: [j][r*64+lane]

  // ---- inline class softmax (keep first NC of NCP1) ----
  if (tid < NQ) {
    const float* cl = cls + (b * NQ + tid) * NCP1;
    float a0 = cl[0], a1 = cl[1], a2 = cl[2];
    float mx = fmaxf(a0, fmaxf(a1, a2));
    const float L2E = 1.4426950408889634f;
    float e0 = EXP2F((a0 - mx) * L2E);
    float e1 = EXP2F((a1 - mx) * L2E);
    float e2 = EXP2F((a2 - mx) * L2E);
    float inv = RCPF(e0 + e1 + e2);
    pq[tid] = make_float2(e0 * inv, e1 * inv);
  }
  __syncthreads();

  const int wave = tid >> 6;    // 0..7
  const int r    = wave & 3;    // output row phase (y = 4k+r)
  const int qh   = wave >> 2;   // q half: 0 -> q 0..49, 1 -> q 50..99
  const int lane = tid & 63;    // col group: x = 8*lane .. 8*lane+7
  const int q0   = qh * NQH;

  // clamped input rows + vertical weights (pre-scaled by -log2e so
  // sigmoid(x) = rcp(1 + exp2(v)), v = -log2e * x)
  const int rlo = (r < 2) ? (k > 0 ? k - 1 : 0) : k;
  const int rhi = (r < 2) ? k : (k < HIN - 1 ? k + 1 : HIN - 1);
  const float NL2E = -1.4426950408889634f;
  const float wlo = ((r == 0) ? 0.375f : (r == 1) ? 0.125f
                   : (r == 2) ? 0.875f : 0.625f) * NL2E;
  const float whi = ((r == 0) ? 0.625f : (r == 1) ? 0.875f
                   : (r == 2) ? 0.125f : 0.375f) * NL2E;

  // 32-bit byte voffsets with the q-half folded in (max ~6.6MB, fits 32b);
  // saddr stays block-uniform.
  const int voffA = q0 * QBYTES + (rlo * WIN + 2 * lane) * 4;
  const int voffB = q0 * QBYTES + (rhi * WIN + 2 * lane) * 4;
  const float* const basep = masks + (size_t)b * NQ * QSTR;  // block-uniform

  const int addrL = (lane - 1) << 2;
  const int addrR = (lane + 1) << 2;
  const bool edgeL = (lane == 0);
  const bool edgeR = (lane == 63);

  float c0[8], c1[8];
#pragma unroll
  for (int j = 0; j < 8; ++j) { c0[j] = 0.f; c1[j] = 0.f; }

  // depth-5 pipeline: 2 x float2 per stage (50 = 5*10, divides evenly)
  float2 A0, B0, A1, B1, A2, B2, A3, B3, A4, B4;

  // saddr-form loads: uniform SGPR-pair base + 32-bit VGPR voffset.
  // qrel*QBYTES is scalar math; one v_add per operand.  =&v: early-clobber
  // so dests can't alias the address operands (R11's second error).
#define LOADSET(S, qrel)                                                  \
  do {                                                                    \
    asm volatile("global_load_dwordx2 %0, %2, %3\n\t"                     \
                 "global_load_dwordx2 %1, %4, %3"                         \
                 : "=&v"(A##S), "=&v"(B##S)                               \
                 : "v"(voffA + (qrel) * QBYTES), "s"(basep),              \
                   "v"(voffB + (qrel) * QBYTES));                         \
  } while (0)

  // steady state: 10 loads outstanding; stage S's pair is oldest -> wait
  // until <=8 remain.  Tied to stage regs so uses can't be hoisted above.
#define WAITS(S)                                                          \
  asm volatile("s_waitcnt vmcnt(8)" : "+v"(A##S), "+v"(B##S))

#define COMPUTE(S, qq)                                                    \
  do {                                                                    \
    const float2 pd = pq[qq];                                             \
    float t0 = fmaf(wlo, A##S.x, whi * B##S.x);   /* col 2c   */          \
    float t1 = fmaf(wlo, A##S.y, whi * B##S.y);   /* col 2c+1 */          \
    float tLr = bperm(addrL, t1);                                         \
    float tRr = bperm(addrR, t0);                                         \
    float tL = edgeL ? t0 : tLr;                                          \
    float tR = edgeR ? t1 : tRr;                                          \
    float dm = tL - t0, dd = t1 - t0, dp = tR - t1;                       \
    float v0 = fmaf(0.375f, dm, t0);                                      \
    float v1 = fmaf(0.125f, dm, t0);                                      \
    float v2 = fmaf(0.125f, dd, t0);                                      \
    float v3 = fmaf(0.375f, dd, t0);                                      \
    float v4 = fmaf(0.625f, dd, t0);                                      \
    float v5 = fmaf(0.875f, dd, t0);                                      \
    float v6 = fmaf(0.125f, dp, t1);                                      \
    float v7 = fmaf(0.375f, dp, t1);                                      \
    float s0 = RCPF(1.0f + EXP2F(v0));                                    \
    float s1 = RCPF(1.0f + EXP2F(v1));                                    \
    float s2 = RCPF(1.0f + EXP2F(v2));                                    \
    float s3 = RCPF(1.0f + EXP2F(v3));                                    \
    float s4 = RCPF(1.0f + EXP2F(v4));                                    \
    float s5 = RCPF(1.0f + EXP2F(v5));                                    \
    float s6 = RCPF(1.0f + EXP2F(v6));                                    \
    float s7 = RCPF(1.0f + EXP2F(v7));                                    \
    c0[0] = fmaf(pd.x, s0, c0[0]);  c1[0] = fmaf(pd.y, s0, c1[0]);        \
    c0[1] = fmaf(pd.x, s1, c0[1]);  c1[1] = fmaf(pd.y, s1, c1[1]);        \
    c0[2] = fmaf(pd.x, s2, c0[2]);  c1[2] = fmaf(pd.y, s2, c1[2]);        \
    c0[3] = fmaf(pd.x, s3, c0[3]);  c1[3] = fmaf(pd.y, s3, c1[3]);        \
    c0[4] = fmaf(pd.x, s4, c0[4]);  c1[4] = fmaf(pd.y, s4, c1[4]);        \
    c0[5] = fmaf(pd.x, s5, c0[5]);  c1[5] = fmaf(pd.y, s5, c1[5]);        \
    c0[6] = fmaf(pd.x, s6, c0[6]);  c1[6] = fmaf(pd.y, s6, c1[6]);        \
    c0[7] = fmaf(pd.x, s7, c0[7]);  c1[7] = fmaf(pd.y, s7, c1[7]);        \
  } while (0)

  LOADSET(0, 0); LOADSET(1, 1); LOADSET(2, 2); LOADSET(3, 3); LOADSET(4, 4);

  // main loop: qrel = 0,5,...,40 (each iteration prefetches qrel+5..qrel+9)
  for (int q = 0; q < NQH - 5; q += 5) {
    WAITS(0); COMPUTE(0, q0 + q);     LOADSET(0, q + 5);
    WAITS(1); COMPUTE(1, q0 + q + 1); LOADSET(1, q + 6);
    WAITS(2); COMPUTE(2, q0 + q + 2); LOADSET(2, q + 7);
    WAITS(3); COMPUTE(3, q0 + q + 3); LOADSET(3, q + 8);
    WAITS(4); COMPUTE(4, q0 + q + 4); LOADSET(4, q + 9);
  }

  // tail: drain all loads, then the final 5 stages (qrel 45..49)
  asm volatile("s_waitcnt vmcnt(0)"
               : "+v"(A0), "+v"(B0), "+v"(A1), "+v"(B1), "+v"(A2), "+v"(B2),
                 "+v"(A3), "+v"(B3), "+v"(A4), "+v"(B4));
  COMPUTE(0, q0 + NQH - 5);
  COMPUTE(1, q0 + NQH - 4);
  COMPUTE(2, q0 + NQH - 3);
  COMPUTE(3, q0 + NQH - 2);
  COMPUTE(4, q0 + NQH - 1);

  // ---- combine q-halves through LDS (conflict-free: stride-1 per j) ----
  const int col = r * 64 + lane;
  if (qh == 1) {
#pragma unroll
    for (int j = 0; j < 8; ++j) { part[j][col] = c0[j]; part[j + 8][col] = c1[j]; }
  }
  __syncthreads();
  if (qh == 0) {
#pragma unroll
    for (int j = 0; j < 8; ++j) { c0[j] += part[j][col]; c1[j] += part[j + 8][col]; }

    const int y  = 4 * k + r;
    const int x0 = 8 * lane;
    float* o0 = out + (((size_t)b * NC + 0) * HOUT + y) * WOUT + x0;
    float* o1 = out + (((size_t)b * NC + 1) * HOUT + y) * WOUT + x0;
    *(float4*)o0       = make_float4(c0[0], c0[1], c0[2], c0[3]);
    *(float4*)(o0 + 4) = make_float4(c0[4], c0[5], c0[6], c0[7]);
    *(float4*)o1       = make_float4(c1[0], c1[1], c1[2], c1[3]);
    *(float4*)(o1 + 4) = make_float4(c1[4], c1[5], c1[6], c1[7]);
  }
}

extern "C" void kernel_launch(void* const* d_in, const int* in_sizes, int n_in,
                              void* d_out, int out_size, void* d_ws, size_t ws_size,
                              hipStream_t stream) {
  const float* cls   = (const float*)d_in[0];   // [8,100,3] fp32
  const float* masks = (const float*)d_in[1];   // [8,100,128,128] fp32
  float* out = (float*)d_out;                   // [8,2,512,512] fp32
  dim3 grid(HIN, NB);   // 128 k-groups x 8 batches, 8 waves/block
  m2f_fused<<<grid, 512, 0, stream>>>(cls, masks, out);
}